// Round 4
// baseline (426.782 us; speedup 1.0000x reference)
//
#include <hip/hip_runtime.h>
#include <stdint.h>

typedef unsigned long long u64;
typedef short v8s __attribute__((ext_vector_type(8)));   // 8 bf16 (4 VGPRs) — MFMA A/B frag
typedef float v4f __attribute__((ext_vector_type(4)));   // MFMA C/D frag

__device__ __forceinline__ unsigned short f2bf_rne(float f) {
  union { float f; unsigned u; } c; c.f = f;
  unsigned u = c.u;
  u += 0x7fffu + ((u >> 16) & 1u);   // round-to-nearest-even
  return (unsigned short)(u >> 16);
}

// Pre-pack conv2 weights to bf16, split-K layout:
// Wr[h*25600 + c*800 + tap*32 + chh] = w2[c][h*32+chh][tap]
__global__ __launch_bounds__(256) void prepack_w2(
    const float* __restrict__ w2, unsigned short* __restrict__ Wr) {
  int idx = blockIdx.x * 256 + threadIdx.x;
  if (idx >= 32 * 1600) return;
  int c = idx / 1600, rem = idx - c * 1600;
  int h = rem / 800, r2 = rem - h * 800;
  int tap = r2 >> 5, chh = r2 & 31;
  Wr[h * 25600 + c * 800 + r2] = f2bf_rne(w2[(c * 64 + h * 32 + chh) * 25 + tap]);
}

// One block (512 thr = 8 waves) per image, fully fused incl. fc.
// LDS map (dynamic, 75776 B -> 2 blocks/CU):
//   Xs    @0:     bf16[900 pix][36 shorts] (32 ch + pad), pixel stride 72 B
//                 -> B-fragments are two 8B-aligned ds_read_b64 per lane.
//   P4    @64800: float[4 cout][2 cin][5 rows][61]   (9760 B)
//   repmask[30]   @74560, repsig[30] @74680, nrep @74800
//   partial[208]  @74816, fs[32] @75648
//   Cout (alias Xs): float[16 ch][677] per m-half.
__global__ __launch_bounds__(512, 4) void fused_kernel(
    const float* __restrict__ bboxes,   // [16][32][4]
    const int*   __restrict__ pairs,    // [16][64][2]
    const float* __restrict__ w1,       // [64][2][5][5]
    const float* __restrict__ b1,       // [64]
    const unsigned short* __restrict__ Wr, // [2][32][800] bf16
    const float* __restrict__ b2,       // [32]
    const float* __restrict__ fcw,      // [512][32]
    const float* __restrict__ fcb,      // [512]
    float* __restrict__ out)            // [1024][512]
{
  extern __shared__ char smem[];
  float* P4       = (float*)(smem + 64800);
  unsigned* repmaskL = (unsigned*)(smem + 74560);
  unsigned* repsigL  = (unsigned*)(smem + 74680);
  int* nrepL         = (int*)(smem + 74800);
  float* partial     = (float*)(smem + 74816);
  float* fs          = (float*)(smem + 75648);
  float* Cout        = (float*)smem;

  const int n = blockIdx.x, t = threadIdx.x;
  const int lane = t & 63, wv = t >> 6;
  const int q = lane >> 4, ln = lane & 15;

  // ---- phase 1: box pair -> indicator bitmasks (lane = coordinate) ----
  const int bb = n >> 6, rr_ = n & 63;
  const int p0 = pairs[(bb * 64 + rr_) * 2 + 0];
  const int p1 = pairs[(bb * 64 + rr_) * 2 + 1];
  const float* A  = bboxes + (bb * 32 + p0) * 4;
  const float* Bq = bboxes + (bb * 32 + p1) * 4;
  const float ax1 = A[0],  ay1 = A[1],  ax2 = A[2],  ay2 = A[3];
  const float cx1 = Bq[0], cy1 = Bq[1], cx2 = Bq[2], cy2 = Bq[3];
  const float ux1 = fminf(ax1, cx1), uy1 = fminf(ay1, cy1);
  const float ux2 = fmaxf(ax2, cx2), uy2 = fmaxf(ay2, cy2);
  const float uw = fmaxf(ux2 - ux1, 1e-6f), uh = fmaxf(uy2 - uy1, 1e-6f);
  const float g = (float)lane + 0.5f;
  u64 ixs[2], iys[2];
  {
    float X1 = (ax1 - ux1) / uw * 64.f, X2 = (ax2 - ux1) / uw * 64.f;
    float Y1 = (ay1 - uy1) / uh * 64.f, Y2 = (ay2 - uy1) / uh * 64.f;
    ixs[0] = __ballot(g >= X1 && g <= X2);
    iys[0] = __ballot(g >= Y1 && g <= Y2);
  }
  {
    float X1 = (cx1 - ux1) / uw * 64.f, X2 = (cx2 - ux1) / uw * 64.f;
    float Y1 = (cy1 - uy1) / uh * 64.f, Y2 = (cy2 - uy1) / uh * 64.f;
    ixs[1] = __ballot(g >= X1 && g <= X2);
    iys[1] = __ballot(g >= Y1 && g <= Y2);
  }

  // ---- phase 1.5: pooled-row regime discovery (wave 0, once per image) ----
  // sig(qy) = the 4 five-bit y-window masks; identical sig => identical pooled
  // conv1 row for every channel.
  if (wv == 0) {
    unsigned sig;
    if (lane < 30) {
      unsigned m00 = (unsigned)(iys[0] >> (2 * lane))     & 31u;
      unsigned m01 = (unsigned)(iys[0] >> (2 * lane + 1)) & 31u;
      unsigned m10 = (unsigned)(iys[1] >> (2 * lane))     & 31u;
      unsigned m11 = (unsigned)(iys[1] >> (2 * lane + 1)) & 31u;
      sig = m00 | (m01 << 5) | (m10 << 10) | (m11 << 15);
    } else sig = 0x80000000u | (unsigned)lane;   // unique sentinel
    int myrep = lane;
    for (int k = 0; k < 30; k++) {
      unsigned sk = (unsigned)__shfl((int)sig, k);
      if (sk == sig && k < myrep) myrep = k;
    }
    u64 repsb = __ballot(myrep == lane && lane < 30);
    if (lane < 30) repmaskL[lane] = 0u;
    if (lane < 30) {
      int j = __popcll(repsb & ((1ull << myrep) - 1));
      atomicOr(&repmaskL[j], 1u << lane);
      if (myrep == lane) repsigL[j] = sig;
    }
    if (lane == 0) nrepL[0] = (int)__popcll(repsb);
  }
  __syncthreads();
  const int nrep = nrepL[0];

  // ---- conv2 MFMA job setup (n-tiles of 16 pixels, 43 tiles) ----
  v4f acc[6][2];
  int pclamp[6], baseB[6];
  int cnt = 0;
  #pragma unroll
  for (int it = 0; it < 6; it++) {
    int nt = wv + it * 8;
    if (nt < 43) {
      int p = nt * 16 + ln; if (p > 675) p = 675;   // dup-compute pad lanes
      pclamp[it] = p;
      int y = p / 26, x = p - y * 26;
      baseB[it] = (y * 30 + x) * 72 + q * 16;
      cnt = it + 1;
    } else { pclamp[it] = 0; baseB[it] = 0; }
    acc[it][0] = (v4f)0.f; acc[it][1] = (v4f)0.f;
  }

  // ---- split-K passes over input-channel halves ----
  for (int h = 0; h < 2; h++) {
    // phase 2: conv1(+pool) for 32 out channels -> Xs, 8 sub-chunks of 4
    for (int c4 = 0; c4 < 8; c4++) {
      const int cbase = h * 32 + c4 * 4;
      // 2a) prefix tables P[cidx][cin], rows r=0..4 = prefix through row r
      for (int e = t; e < 480; e += 512) {
        int cidx = e / 120, rem = e - cidx * 120;
        int ch = rem / 60, x = rem - ch * 60;
        unsigned bits = (unsigned)(ixs[ch] >> x) & 31u;
        const float* wr = w1 + (cbase + cidx) * 50 + ch * 25;
        float* Pp = P4 + (cidx * 2 + ch) * 305 + x;
        float p = 0.f;
        #pragma unroll
        for (int i = 0; i < 5; i++) {
          float rcv = 0.f;
          #pragma unroll
          for (int j = 0; j < 5; j++)
            rcv += ((bits >> j) & 1u) ? wr[i * 5 + j] : 0.f;
          p += rcv;
          Pp[i * 61] = p;
        }
      }
      __syncthreads();   // P ready; also fences prior phase-3 Xs reads
      // 2b) one item per (regime, cidx, qx): compute pooled value once,
      //     scatter b16 to every row of the regime.
      for (int e = t; e < nrep * 120; e += 512) {
        int r = e / 120, rem = e - r * 120;
        int cidx = rem / 30, qx = rem - cidx * 30;
        unsigned sig = repsigL[r];
        float v00 = 0.f, v01 = 0.f, v10 = 0.f, v11 = 0.f;
        #pragma unroll
        for (int ch = 0; ch < 2; ch++) {
          const float* Pc = P4 + (cidx * 2 + ch) * 305 + 2 * qx;
          #pragma unroll
          for (int dy = 0; dy < 2; dy++) {
            unsigned m = (sig >> (ch * 10 + dy * 5)) & 31u;
            bool act = m != 0;
            int zrow = 31 - __clz((int)(m | 1u));
            int a = __ffs((int)m) - 1;
            bool sub = a > 0;
            int arow = sub ? a - 1 : 0;
            float z0 = Pc[zrow * 61], z1 = Pc[zrow * 61 + 1];
            float a0v = Pc[arow * 61], a1v = Pc[arow * 61 + 1];
            float d0 = act ? (z0 - (sub ? a0v : 0.f)) : 0.f;
            float d1 = act ? (z1 - (sub ? a1v : 0.f)) : 0.f;
            if (dy == 0) { v00 += d0; v01 += d1; }
            else         { v10 += d0; v11 += d1; }
          }
        }
        float mx = fmaxf(fmaxf(v00, v01), fmaxf(v10, v11)) + b1[cbase + cidx];
        unsigned short val = f2bf_rne(mx);
        int base = qx * 72 + (c4 * 4 + cidx) * 2;   // byte offset within a row
        unsigned m = repmaskL[r];
        while (m) {
          int qy = __ffs((int)m) - 1; m &= m - 1;
          *(unsigned short*)(smem + qy * 2160 + base) = val;
        }
      }
      __syncthreads();
    }

    // phase 3: conv2 implicit-GEMM, K-half = 25 taps x 32 ch (25 s-steps)
    const unsigned short* pA0 = Wr + h * 25600 + ln * 800 + q * 8;
    const unsigned short* pA1 = pA0 + 16 * 800;
    for (int i = 0; i < 5; i++) {
      const int rowoff = i * 2160;            // i*30*72 bytes
      #pragma unroll
      for (int jt = 0; jt < 5; jt++) {
        const int s = i * 5 + jt;
        v8s a0 = *(const v8s*)(pA0 + s * 32);
        v8s a1 = *(const v8s*)(pA1 + s * 32);
        const int off = rowoff + jt * 72;
        #pragma unroll
        for (int it = 0; it < 6; it++) {
          if (it < cnt) {
            uint2 lo = *(const uint2*)(smem + (baseB[it] + off));
            uint2 hi = *(const uint2*)(smem + (baseB[it] + off + 8));
            uint4 bv; bv.x = lo.x; bv.y = lo.y; bv.z = hi.x; bv.w = hi.y;
            v8s b = __builtin_bit_cast(v8s, bv);
            acc[it][0] = __builtin_amdgcn_mfma_f32_16x16x32_bf16(a0, b, acc[it][0], 0, 0, 0);
            acc[it][1] = __builtin_amdgcn_mfma_f32_16x16x32_bf16(a1, b, acc[it][1], 0, 0, 0);
          }
        }
      }
    }
  }

  // ---- phase 4: per m-half, pool2 + mean + bias -> fs[32] (LDS) ----
  #pragma unroll
  for (int mt = 0; mt < 2; mt++) {
    __syncthreads();               // prior Xs/Cout readers done
    #pragma unroll
    for (int it = 0; it < 6; it++) {
      if (it < cnt) {
        #pragma unroll
        for (int r = 0; r < 4; r++)
          Cout[(q * 4 + r) * 677 + pclamp[it]] = acc[it][mt][r];
      }
    }
    __syncthreads();
    if (t < 208) {
      int c = t & 15, py = t >> 4;
      const float* r0 = Cout + c * 677 + (2 * py) * 26;
      const float* r1 = r0 + 26;
      float s = 0.f;
      #pragma unroll
      for (int px = 0; px < 13; px++) {
        float m0 = fmaxf(r0[2 * px], r0[2 * px + 1]);
        float m1 = fmaxf(r1[2 * px], r1[2 * px + 1]);
        s += fmaxf(m0, m1);
      }
      partial[t] = s;
    }
    __syncthreads();
    if (t < 16) {
      float s = 0.f;
      #pragma unroll
      for (int k = 0; k < 13; k++) s += partial[k * 16 + t];
      fs[mt * 16 + t] = s * (1.f / 169.f) + b2[mt * 16 + t];
    }
  }
  __syncthreads();

  // ---- phase 5: fc (512 outs, thread t -> out column t), relu ----
  {
    const float* wrow = fcw + t * 32;
    float d = 0.f;
    #pragma unroll
    for (int k = 0; k < 32; k++) d += wrow[k] * fs[k];
    out[(u64)n * 512 + t] = fmaxf(d + fcb[t], 0.f);
  }
}

extern "C" void kernel_launch(void* const* d_in, const int* in_sizes, int n_in,
                              void* d_out, int out_size, void* d_ws, size_t ws_size,
                              hipStream_t stream) {
  const float* bboxes = (const float*)d_in[0];
  // d_in[1] = num_obj, d_in[2] = num_relation: constants, unused by the math
  const int*   pairs  = (const int*)  d_in[3];
  const float* w1     = (const float*)d_in[4];
  const float* b1     = (const float*)d_in[5];
  const float* w2     = (const float*)d_in[6];
  const float* b2     = (const float*)d_in[7];
  const float* fcw    = (const float*)d_in[8];
  const float* fcb    = (const float*)d_in[9];
  float* out = (float*)d_out;

  unsigned short* Wr = (unsigned short*)d_ws;   // 102400 B

  prepack_w2<<<(32 * 1600 + 255) / 256, 256, 0, stream>>>(w2, Wr);
  fused_kernel<<<1024, 512, 75776, stream>>>(bboxes, pairs, w1, b1, Wr, b2,
                                             fcw, fcb, out);
}

// Round 5
// 395.582 us; speedup vs baseline: 1.0789x; 1.0789x over previous
//
#include <hip/hip_runtime.h>
#include <stdint.h>

typedef unsigned long long u64;
typedef short v8s __attribute__((ext_vector_type(8)));   // 8 bf16 (4 VGPRs) — MFMA A/B frag
typedef float v4f __attribute__((ext_vector_type(4)));   // MFMA C/D frag

__device__ __forceinline__ unsigned short f2bf_rne(float f) {
  union { float f; unsigned u; } c; c.f = f;
  unsigned u = c.u;
  u += 0x7fffu + ((u >> 16) & 1u);   // round-to-nearest-even
  return (unsigned short)(u >> 16);
}

// Pre-pack conv2 weights to bf16, split-K layout:
// Wr[h*25600 + c*800 + tap*32 + chh] = w2[c][h*32+chh][tap]
__global__ __launch_bounds__(256) void prepack_w2(
    const float* __restrict__ w2, unsigned short* __restrict__ Wr) {
  int idx = blockIdx.x * 256 + threadIdx.x;
  if (idx >= 32 * 1600) return;
  int c = idx / 1600, rem = idx - c * 1600;
  int h = rem / 800, r2 = rem - h * 800;
  int tap = r2 >> 5, chh = r2 & 31;
  Wr[h * 25600 + c * 800 + r2] = f2bf_rne(w2[(c * 64 + h * 32 + chh) * 25 + tap]);
}

// One block (512 thr = 8 waves) per image, fully fused incl. fc.
// LDS map (dynamic, 77280 B -> 2 blocks/CU):
//   Xs @0:      bf16[900 pix][36 shorts], pixel stride 72 B. B-fragments are
//               two 8B-aligned b64 reads; quarter-wave (16 same-q lanes) hits
//               banks 18*ln mod 32 = 16 distinct even banks -> conflict-free
//               (validated r4: conflicts 3.55e7 -> 1.45e7 with this layout).
//   P4 @64800:  float[4 cout][2 cin][6 rows][60]; row 0 = 0 so every pooled
//               value is P[zrow]-P[arow] with no flags.   (11520 B)
//   partial @76320 (832 B), fs @77152 (128 B). Cout aliases Xs in phase 4.
__global__ __launch_bounds__(512, 4) void fused_kernel(
    const float* __restrict__ bboxes,   // [16][32][4]
    const int*   __restrict__ pairs,    // [16][64][2]
    const float* __restrict__ w1,       // [64][2][5][5]
    const float* __restrict__ b1,       // [64]
    const unsigned short* __restrict__ Wr, // [2][32][800] bf16
    const float* __restrict__ b2,       // [32]
    const float* __restrict__ fcw,      // [512][32]
    const float* __restrict__ fcb,      // [512]
    float* __restrict__ out)            // [1024][512]
{
  extern __shared__ char smem[];
  float* P4      = (float*)(smem + 64800);
  float* partial = (float*)(smem + 76320);
  float* fs      = (float*)(smem + 77152);
  float* Cout    = (float*)smem;

  const int n = blockIdx.x, t = threadIdx.x;
  const int lane = t & 63, wv = t >> 6;
  const int q = lane >> 4, ln = lane & 15;

  // ---- phase 1: box pair -> indicator bitmasks (lane = coordinate) ----
  const int bb = n >> 6, rr_ = n & 63;
  const int p0 = pairs[(bb * 64 + rr_) * 2 + 0];
  const int p1 = pairs[(bb * 64 + rr_) * 2 + 1];
  const float* A  = bboxes + (bb * 32 + p0) * 4;
  const float* Bq = bboxes + (bb * 32 + p1) * 4;
  const float ax1 = A[0],  ay1 = A[1],  ax2 = A[2],  ay2 = A[3];
  const float cx1 = Bq[0], cy1 = Bq[1], cx2 = Bq[2], cy2 = Bq[3];
  const float ux1 = fminf(ax1, cx1), uy1 = fminf(ay1, cy1);
  const float ux2 = fmaxf(ax2, cx2), uy2 = fmaxf(ay2, cy2);
  const float uw = fmaxf(ux2 - ux1, 1e-6f), uh = fmaxf(uy2 - uy1, 1e-6f);
  const float g = (float)lane + 0.5f;
  u64 ixs[2], iys[2];
  {
    float X1 = (ax1 - ux1) / uw * 64.f, X2 = (ax2 - ux1) / uw * 64.f;
    float Y1 = (ay1 - uy1) / uh * 64.f, Y2 = (ay2 - uy1) / uh * 64.f;
    ixs[0] = __ballot(g >= X1 && g <= X2);
    iys[0] = __ballot(g >= Y1 && g <= Y2);
  }
  {
    float X1 = (cx1 - ux1) / uw * 64.f, X2 = (cx2 - ux1) / uw * 64.f;
    float Y1 = (cy1 - uy1) / uh * 64.f, Y2 = (cy2 - uy1) / uh * 64.f;
    ixs[1] = __ballot(g >= X1 && g <= X2);
    iys[1] = __ballot(g >= Y1 && g <= Y2);
  }

  // ---- hoisted per-pixel descriptors (reused by all 16 chunk iterations) ---
  // pooled pixel pp handled by this thread: pix = t + 512*pp  (pix1 may be inactive)
  int qx2_[2], xsb_[2];
  int zo_[2][2][2], ao_[2][2][2];   // [pp][ch][dy] dword offsets = row*60
  bool same_[2][2];
  #pragma unroll
  for (int pp = 0; pp < 2; pp++) {
    int pix = t + pp * 512;
    bool vld = pix < 900;
    int qy = vld ? pix / 30 : 0;
    int qx = vld ? pix - qy * 30 : 0;
    qx2_[pp] = 2 * qx;
    xsb_[pp] = pix * 72;
    #pragma unroll
    for (int ch = 0; ch < 2; ch++) {
      unsigned m0 = (unsigned)(iys[ch] >> (2 * qy))     & 31u;
      unsigned m1 = (unsigned)(iys[ch] >> (2 * qy + 1)) & 31u;
      zo_[pp][ch][0] = (m0 ? 32 - __clz((int)m0) : 0) * 60;
      ao_[pp][ch][0] = (m0 ? __ffs((int)m0) - 1  : 0) * 60;
      zo_[pp][ch][1] = (m1 ? 32 - __clz((int)m1) : 0) * 60;
      ao_[pp][ch][1] = (m1 ? __ffs((int)m1) - 1  : 0) * 60;
      same_[pp][ch] = (m0 == m1);
    }
  }

  // ---- conv2 MFMA job setup (n-tiles of 16 pixels, 43 tiles) ----
  v4f acc[6][2];
  int pclamp[6], baseB[6];
  int cnt = 0;
  #pragma unroll
  for (int it = 0; it < 6; it++) {
    int nt = wv + it * 8;
    if (nt < 43) {
      int p = nt * 16 + ln; if (p > 675) p = 675;   // dup-compute pad lanes
      pclamp[it] = p;
      int y = p / 26, x = p - y * 26;
      baseB[it] = (y * 30 + x) * 72 + q * 16;
      cnt = it + 1;
    } else { pclamp[it] = 0; baseB[it] = 0; }
    acc[it][0] = (v4f)0.f; acc[it][1] = (v4f)0.f;
  }

  // ---- split-K passes over input-channel halves ----
  for (int h = 0; h < 2; h++) {
    // phase 2: conv1(+pool) for 32 out channels -> Xs, 8 chunks of 4 couts
    for (int c4 = 0; c4 < 8; c4++) {
      const int cbase = h * 32 + c4 * 4;
      // 2a) prefix tables: P[cidx][ch] row 0 = 0, rows 1..5 = prefix sums
      for (int e = t; e < 480; e += 512) {
        int cidx = e / 120, rem = e - cidx * 120;
        int ch = rem / 60, x = rem - ch * 60;
        unsigned bits = (unsigned)(ixs[ch] >> x) & 31u;
        const float* wr = w1 + (cbase + cidx) * 50 + ch * 25;
        float* Pp = P4 + (cidx * 2 + ch) * 360 + x;
        float p = 0.f;
        Pp[0] = 0.f;
        #pragma unroll
        for (int i = 0; i < 5; i++) {
          float rcv = 0.f;
          #pragma unroll
          for (int j = 0; j < 5; j++)
            rcv += ((bits >> j) & 1u) ? wr[i * 5 + j] : 0.f;
          p += rcv;
          Pp[(i + 1) * 60] = p;
        }
      }
      __syncthreads();   // P ready; also fences prior phase-3 Xs reads
      // 2b) pooled conv1 outputs -> Xs bf16 (4 couts, unconditional b64 reads)
      float b1v[4];
      #pragma unroll
      for (int i = 0; i < 4; i++) b1v[i] = b1[cbase + i];
      #pragma unroll
      for (int pp = 0; pp < 2; pp++) {
        int pix = t + pp * 512;
        if (pix < 900) {
          unsigned outs[2];
          #pragma unroll
          for (int cidx = 0; cidx < 4; cidx++) {
            float v00 = 0.f, v01 = 0.f, v10 = 0.f, v11 = 0.f;
            #pragma unroll
            for (int ch = 0; ch < 2; ch++) {
              const float* Pc = P4 + (cidx * 2 + ch) * 360 + qx2_[pp];
              float2 z0 = *(const float2*)(Pc + zo_[pp][ch][0]);
              float2 a0 = *(const float2*)(Pc + ao_[pp][ch][0]);
              float d0 = z0.x - a0.x, d1 = z0.y - a0.y;
              v00 += d0; v01 += d1;
              if (same_[pp][ch]) { v10 += d0; v11 += d1; }
              else {
                float2 z1 = *(const float2*)(Pc + zo_[pp][ch][1]);
                float2 a1 = *(const float2*)(Pc + ao_[pp][ch][1]);
                v10 += z1.x - a1.x; v11 += z1.y - a1.y;
              }
            }
            float mx = fmaxf(fmaxf(v00, v01), fmaxf(v10, v11)) + b1v[cidx];
            unsigned bf = (unsigned)f2bf_rne(mx);
            if ((cidx & 1) == 0) outs[cidx >> 1] = bf;
            else                 outs[cidx >> 1] |= bf << 16;
          }
          uint2 pk; pk.x = outs[0]; pk.y = outs[1];
          *(uint2*)(smem + xsb_[pp] + c4 * 8) = pk;   // 8B aligned
        }
      }
      __syncthreads();
    }

    // phase 3: conv2 implicit-GEMM, K-half = 25 taps x 32 ch (25 s-steps)
    const unsigned short* pA0 = Wr + h * 25600 + ln * 800 + q * 8;
    const unsigned short* pA1 = pA0 + 16 * 800;
    for (int i = 0; i < 5; i++) {
      const int rowoff = i * 2160;            // i*30*72 bytes
      #pragma unroll
      for (int jt = 0; jt < 5; jt++) {
        const int s = i * 5 + jt;
        v8s a0 = *(const v8s*)(pA0 + s * 32);
        v8s a1 = *(const v8s*)(pA1 + s * 32);
        const int off = rowoff + jt * 72;
        #pragma unroll
        for (int it = 0; it < 6; it++) {
          if (it < cnt) {
            uint2 lo = *(const uint2*)(smem + (baseB[it] + off));
            uint2 hi = *(const uint2*)(smem + (baseB[it] + off + 8));
            uint4 bv; bv.x = lo.x; bv.y = lo.y; bv.z = hi.x; bv.w = hi.y;
            v8s b = __builtin_bit_cast(v8s, bv);
            acc[it][0] = __builtin_amdgcn_mfma_f32_16x16x32_bf16(a0, b, acc[it][0], 0, 0, 0);
            acc[it][1] = __builtin_amdgcn_mfma_f32_16x16x32_bf16(a1, b, acc[it][1], 0, 0, 0);
          }
        }
      }
    }
  }

  // ---- phase 4: per m-half, pool2 + mean + bias -> fs[32] (LDS) ----
  #pragma unroll
  for (int mt = 0; mt < 2; mt++) {
    __syncthreads();               // prior Xs/Cout readers done
    #pragma unroll
    for (int it = 0; it < 6; it++) {
      if (it < cnt) {
        #pragma unroll
        for (int r = 0; r < 4; r++)
          Cout[(q * 4 + r) * 677 + pclamp[it]] = acc[it][mt][r];
      }
    }
    __syncthreads();
    if (t < 208) {
      int c = t & 15, py = t >> 4;
      const float* r0 = Cout + c * 677 + (2 * py) * 26;
      const float* r1 = r0 + 26;
      float s = 0.f;
      #pragma unroll
      for (int px = 0; px < 13; px++) {
        float m0 = fmaxf(r0[2 * px], r0[2 * px + 1]);
        float m1 = fmaxf(r1[2 * px], r1[2 * px + 1]);
        s += fmaxf(m0, m1);
      }
      partial[t] = s;
    }
    __syncthreads();
    if (t < 16) {
      float s = 0.f;
      #pragma unroll
      for (int k = 0; k < 13; k++) s += partial[k * 16 + t];
      fs[mt * 16 + t] = s * (1.f / 169.f) + b2[mt * 16 + t];
    }
  }
  __syncthreads();

  // ---- phase 5: fc (512 outs, thread t -> out column t), relu ----
  {
    const float* wrow = fcw + t * 32;
    float d = 0.f;
    #pragma unroll
    for (int k = 0; k < 32; k++) d += wrow[k] * fs[k];
    out[(u64)n * 512 + t] = fmaxf(d + fcb[t], 0.f);
  }
}

extern "C" void kernel_launch(void* const* d_in, const int* in_sizes, int n_in,
                              void* d_out, int out_size, void* d_ws, size_t ws_size,
                              hipStream_t stream) {
  const float* bboxes = (const float*)d_in[0];
  // d_in[1] = num_obj, d_in[2] = num_relation: constants, unused by the math
  const int*   pairs  = (const int*)  d_in[3];
  const float* w1     = (const float*)d_in[4];
  const float* b1     = (const float*)d_in[5];
  const float* w2     = (const float*)d_in[6];
  const float* b2     = (const float*)d_in[7];
  const float* fcw    = (const float*)d_in[8];
  const float* fcb    = (const float*)d_in[9];
  float* out = (float*)d_out;

  unsigned short* Wr = (unsigned short*)d_ws;   // 102400 B

  prepack_w2<<<(32 * 1600 + 255) / 256, 256, 0, stream>>>(w2, Wr);
  fused_kernel<<<1024, 512, 77280, stream>>>(bboxes, pairs, w1, b1, Wr, b2,
                                             fcw, fcb, out);
}